// Round 12
// baseline (2978.612 us; speedup 1.0000x reference)
//
#include <hip/hip_runtime.h>
#include <stdint.h>

#define NB 8
#define NPT 16384
#define NM 1024
#define NK 32

// ws layout (float element offsets)
#define WS_W0T 0                    // 67*64 = 4288   W0t[c][o] = W0[o][c]*s0[o]
#define WS_B0  (WS_W0T + 4288)      // 64             b0*s0+t0
#define WS_W1T (WS_B0 + 64)         // 64*128 = 8192
#define WS_B1  (WS_W1T + 8192)      // 128
#define WS_W2T (WS_B1 + 128)        // 128*256 = 32768
#define WS_B2  (WS_W2T + 32768)     // 256
#define WS_IDX (WS_B2 + 256)        // 8192 ints (FPS indices)
#define WS_NXYZ (WS_IDX + 8192)     // 8*1024*3 = 24576 floats
#define WS_BALL (WS_NXYZ + 24576)   // 8*1024*32 = 262144 ints

// out layout (float element offsets)
#define OUT_XYZ 0
#define OUT_FEAT 24576
#define OUT_IDX (24576 + 2097152)

// ---------------- weight prep: transpose + fold BN scale ----------------
__global__ void prep_weights(const float* __restrict__ W0, const float* __restrict__ b0,
                             const float* __restrict__ s0, const float* __restrict__ t0,
                             const float* __restrict__ W1, const float* __restrict__ b1,
                             const float* __restrict__ s1, const float* __restrict__ t1,
                             const float* __restrict__ W2, const float* __restrict__ b2,
                             const float* __restrict__ s2, const float* __restrict__ t2,
                             float* __restrict__ ws) {
    int id = blockIdx.x * 256 + threadIdx.x;
    if (id < 4288) { int c = id >> 6, o = id & 63;  ws[WS_W0T + id] = W0[o * 67 + c] * s0[o]; return; }
    id -= 4288;
    if (id < 64)   { ws[WS_B0 + id] = fmaf(b0[id], s0[id], t0[id]); return; }
    id -= 64;
    if (id < 8192) { int c = id >> 7, o = id & 127; ws[WS_W1T + id] = W1[o * 64 + c] * s1[o]; return; }
    id -= 8192;
    if (id < 128)  { ws[WS_B1 + id] = fmaf(b1[id], s1[id], t1[id]); return; }
    id -= 128;
    if (id < 32768){ int c = id >> 8, o = id & 255; ws[WS_W2T + id] = W2[o * 128 + c] * s2[o]; return; }
    id -= 32768;
    if (id < 256)  { ws[WS_B2 + id] = fmaf(b2[id], s2[id], t2[id]); return; }
}

#define FOREACH16(M) M(0) M(1) M(2) M(3) M(4) M(5) M(6) M(7) \
                     M(8) M(9) M(10) M(11) M(12) M(13) M(14) M(15)

// bit-exact uniform broadcast to SGPR (R10 bug: raw readfirstlane(float) did a
// NUMERIC float->uint conversion; must bit-cast).
__device__ __forceinline__ float bcast_first(float x) {
    return __uint_as_float(__builtin_amdgcn_readfirstlane(__float_as_uint(x)));
}

// ---------------- farthest point sampling v6: LDS-resident payload ----------------
// R2-R11 conclusion: the backend caps this kernel shape at ~92 VGPRs and spills the
// point payload to L2-backed scratch no matter how it's expressed (arrays, named
// scalars, AGPR pins, alias-blocking) -> ~4150 cyc/iter, L2-latency/BW-bound.
// fps6 stops demanding register residency: (x,y) of all 16384 points live in LDS
// (float2[16384] = 128 KB, fits in 160 KB), z + dd stay in 32 named scalars (~60
// VGPR, under the observed clamp -> no spill). Re-reading LDS is the design:
// 16 ds_read_b64/thread/iter, consecutive lanes -> consecutive 8B -> 2 lanes/bank
// = conflict-free. LDS floor ~1024 cyc/iter vs the ~2300 cyc L2 path it replaces.
// Distance math unchanged (_rn, no FMA) -> bit-matches reference; packed u64
// (dist bits | ~idx) argmax = unsigned max, first-index tie-break; one barrier/iter.
__global__ __attribute__((amdgpu_flat_work_group_size(1024, 1024)))
void fps6_kernel(const float* __restrict__ xyz, int* __restrict__ out_idx) {
    __shared__ float2 pxy[NPT];          // 128 KB
    __shared__ uint64_t s_red[2][16];
    int b = blockIdx.x, t = threadIdx.x;
    const float* __restrict__ Xp = xyz + (size_t)b * NPT * 3;

#define DECL_PT(j) float pz##j, dd##j;
    FOREACH16(DECL_PT)
#undef DECL_PT

#define LOAD_PT(j) { int p = t + (j) * 1024; \
        float x = Xp[p * 3 + 0], y = Xp[p * 3 + 1]; \
        pz##j = Xp[p * 3 + 2]; \
        pxy[p] = make_float2(x, y); \
        dd##j = 1e10f; }
    FOREACH16(LOAD_PT)
#undef LOAD_PT
    __syncthreads();

    int farthest = 0;
    float cx = bcast_first(Xp[0]);
    float cy = bcast_first(Xp[1]);
    float cz = bcast_first(Xp[2]);
    int lane = t & 63, w = t >> 6;
    for (int it = 0; it < NM; ++it) {
        if (t == 0) out_idx[b * NM + it] = farthest;
        float best = -1.0f; int bi = 0;
        // ascending j + strict '>' => first-max wins in-thread (idx = t + j*1024 ascends with j)
#define STEP_PT(j) { \
        float2 q = pxy[t + (j) * 1024]; \
        float dx = __fsub_rn(q.x, cx); \
        float dy = __fsub_rn(q.y, cy); \
        float dz = __fsub_rn(pz##j, cz); \
        float d  = __fadd_rn(__fadd_rn(__fmul_rn(dx, dx), __fmul_rn(dy, dy)), __fmul_rn(dz, dz)); \
        dd##j = fminf(dd##j, d); \
        if (dd##j > best) { best = dd##j; bi = t + (j) * 1024; } }
        FOREACH16(STEP_PT)
#undef STEP_PT
        // pack: high32 = dist bits (positive floats sort as uints), low32 = ~idx (tie -> lower idx)
        uint64_t pk = ((uint64_t)__float_as_uint(best) << 32) | (uint64_t)(uint32_t)(~(uint32_t)bi);
#pragma unroll
        for (int off = 32; off >= 1; off >>= 1) {
            uint64_t o = __shfl_xor(pk, off);
            if (o > pk) pk = o;
        }
        if (lane == 0) s_red[it & 1][w] = pk;
        __syncthreads();
        uint64_t m0 = s_red[it & 1][lane & 15];
#pragma unroll
        for (int off = 1; off < 16; off <<= 1) {
            uint64_t o = __shfl_xor(m0, off);
            if (o > m0) m0 = o;
        }
        int widx = (int)(~(uint32_t)m0);
        farthest = widx;
        const float* cp = Xp + (size_t)widx * 3;   // same addr across wave -> broadcast, L2-hit
        cx = bcast_first(cp[0]);
        cy = bcast_first(cp[1]);
        cz = bcast_first(cp[2]);
    }
}

// ---------------- gather new_xyz + emit indices as float ----------------
__global__ void gather_newxyz(const float* __restrict__ xyz, const int* __restrict__ idx_ws,
                              float* __restrict__ nxyz_ws, float* __restrict__ out_xyz,
                              float* __restrict__ out_idx_f) {
    int id = blockIdx.x * 256 + threadIdx.x;
    if (id >= NB * NM) return;
    int b = id / NM;
    int p = idx_ws[id];
    const float* Xp = xyz + ((size_t)b * NPT + p) * 3;
    float x = Xp[0], y = Xp[1], z = Xp[2];
    nxyz_ws[id * 3 + 0] = x; nxyz_ws[id * 3 + 1] = y; nxyz_ws[id * 3 + 2] = z;
    out_xyz[id * 3 + 0] = x; out_xyz[id * 3 + 1] = y; out_xyz[id * 3 + 2] = z;
    out_idx_f[id] = (float)p;
}

// ---------------- ball query: first 32 in-radius indices (ascending) ----------------
__global__ __launch_bounds__(256) void ball_query_kernel(const float* __restrict__ xyz,
                                                         const float* __restrict__ nxyz,
                                                         int* __restrict__ ball) {
    int blk = blockIdx.x;
    int b = blk >> 10;
    int t = threadIdx.x;
    const float* Xp = xyz + (size_t)b * NPT * 3;
    float cx = nxyz[blk * 3 + 0], cy = nxyz[blk * 3 + 1], cz = nxyz[blk * 3 + 2];
    const float r2 = (float)(0.4 * 0.4);
    uint64_t mask = 0;
    int base = t * 64;
    const float4* q = (const float4*)(Xp + (size_t)base * 3);
#pragma unroll 4
    for (int c = 0; c < 16; c++) {
        float4 A = q[c * 3 + 0], B = q[c * 3 + 1], C = q[c * 3 + 2];
        float xs[4] = {A.x, A.w, B.z, C.y};
        float ys[4] = {A.y, B.x, B.w, C.z};
        float zs[4] = {A.z, B.y, C.x, C.w};
#pragma unroll
        for (int u = 0; u < 4; u++) {
            float dx = __fsub_rn(xs[u], cx);
            float dy = __fsub_rn(ys[u], cy);
            float dz = __fsub_rn(zs[u], cz);
            float d2 = __fadd_rn(__fadd_rn(__fmul_rn(dx, dx), __fmul_rn(dy, dy)), __fmul_rn(dz, dz));
            if (d2 <= r2) mask |= (1ull << (c * 4 + u));
        }
    }
    int cnt = __popcll(mask);
    int scan = cnt;
    for (int off = 1; off < 64; off <<= 1) {
        int nv = __shfl_up(scan, off);
        if ((t & 63) >= off) scan += nv;
    }
    __shared__ int s_wsum[4];
    __shared__ int s_hit[32];
    int w = t >> 6;
    if ((t & 63) == 63) s_wsum[w] = scan;
    __syncthreads();
    int woff = 0;
    for (int i = 0; i < 4; i++) if (i < w) woff += s_wsum[i];
    int excl = woff + scan - cnt;
    uint64_t mm = mask; int pos = excl;
    while (mm && pos < 32) {
        int j = __ffsll((long long)mm) - 1;
        s_hit[pos] = base + j;
        pos++;
        mm &= mm - 1;
    }
    __syncthreads();
    int total = s_wsum[0] + s_wsum[1] + s_wsum[2] + s_wsum[3];
    if (t < 32) {
        int first = s_hit[0];
        ball[blk * NK + t] = (t < total) ? s_hit[t] : first;
    }
}

// ---------------- fused group + 3xMLP + max over K ----------------
__global__ __attribute__((amdgpu_flat_work_group_size(256, 256), amdgpu_waves_per_eu(2, 2)))
void fused_mlp_kernel(const float* __restrict__ xyz,
                      const float* __restrict__ feats,
                      const float* __restrict__ ws_f,
                      const int* __restrict__ ball,
                      const float* __restrict__ nxyz,
                      float* __restrict__ out_feat) {
    int blk = blockIdx.x;
    int b = blk >> 9;
    int m0 = (blk & 511) * 2;
    int t = threadIdx.x;
    int k = t & 31, g = t >> 5;
    __shared__ float Xs[2][67][32];
    __shared__ float h1[2][64][32];
    __shared__ float h2[2][128][32];
    __shared__ int sidx[2][32];
    const float* W0t = ws_f + WS_W0T; const float* b0f = ws_f + WS_B0;
    const float* W1t = ws_f + WS_W1T; const float* b1f = ws_f + WS_B1;
    const float* W2t = ws_f + WS_W2T; const float* b2f = ws_f + WS_B2;

    if (t < 64) {
        int ctr = t >> 5;
        sidx[ctr][t & 31] = ball[((size_t)b * NM + m0 + ctr) * NK + (t & 31)];
    }
    __syncthreads();

    const float* Xp = xyz + (size_t)b * NPT * 3;
    if (g < 6) {
        int ctr = g / 3, dim = g % 3;
        float cc = nxyz[((size_t)b * NM + m0 + ctr) * 3 + dim];
        Xs[ctr][dim][k] = Xp[sidx[ctr][k] * 3 + dim] - cc;
    }
    const float* Fp = feats + (size_t)b * 64 * NPT;
#pragma unroll
    for (int i = 0; i < 8; i++) {
        int c = g + 8 * i;
        Xs[0][3 + c][k] = Fp[(size_t)c * NPT + sidx[0][k]];
        Xs[1][3 + c][k] = Fp[(size_t)c * NPT + sidx[1][k]];
    }
    __syncthreads();

    {
        float acc0[8], acc1[8];
#pragma unroll
        for (int i = 0; i < 8; i++) { acc0[i] = b0f[g * 8 + i]; acc1[i] = acc0[i]; }
#pragma unroll 4
        for (int c = 0; c < 67; c++) {
            float xv0 = Xs[0][c][k], xv1 = Xs[1][c][k];
            const float* wr = W0t + c * 64 + g * 8;
            float4 wa = *(const float4*)(wr), wb = *(const float4*)(wr + 4);
            acc0[0] = fmaf(wa.x, xv0, acc0[0]); acc1[0] = fmaf(wa.x, xv1, acc1[0]);
            acc0[1] = fmaf(wa.y, xv0, acc0[1]); acc1[1] = fmaf(wa.y, xv1, acc1[1]);
            acc0[2] = fmaf(wa.z, xv0, acc0[2]); acc1[2] = fmaf(wa.z, xv1, acc1[2]);
            acc0[3] = fmaf(wa.w, xv0, acc0[3]); acc1[3] = fmaf(wa.w, xv1, acc1[3]);
            acc0[4] = fmaf(wb.x, xv0, acc0[4]); acc1[4] = fmaf(wb.x, xv1, acc1[4]);
            acc0[5] = fmaf(wb.y, xv0, acc0[5]); acc1[5] = fmaf(wb.y, xv1, acc1[5]);
            acc0[6] = fmaf(wb.z, xv0, acc0[6]); acc1[6] = fmaf(wb.z, xv1, acc1[6]);
            acc0[7] = fmaf(wb.w, xv0, acc0[7]); acc1[7] = fmaf(wb.w, xv1, acc1[7]);
        }
#pragma unroll
        for (int i = 0; i < 8; i++) {
            h1[0][g * 8 + i][k] = fmaxf(acc0[i], 0.0f);
            h1[1][g * 8 + i][k] = fmaxf(acc1[i], 0.0f);
        }
    }
    __syncthreads();

    {
        float acc0[16], acc1[16];
#pragma unroll
        for (int i = 0; i < 16; i++) { acc0[i] = b1f[g * 16 + i]; acc1[i] = acc0[i]; }
#pragma unroll 4
        for (int c = 0; c < 64; c++) {
            float xv0 = h1[0][c][k], xv1 = h1[1][c][k];
            const float4* wr = (const float4*)(W1t + c * 128 + g * 16);
#pragma unroll
            for (int q = 0; q < 4; q++) {
                float4 wv = wr[q];
                acc0[q * 4 + 0] = fmaf(wv.x, xv0, acc0[q * 4 + 0]); acc1[q * 4 + 0] = fmaf(wv.x, xv1, acc1[q * 4 + 0]);
                acc0[q * 4 + 1] = fmaf(wv.y, xv0, acc0[q * 4 + 1]); acc1[q * 4 + 1] = fmaf(wv.y, xv1, acc1[q * 4 + 1]);
                acc0[q * 4 + 2] = fmaf(wv.z, xv0, acc0[q * 4 + 2]); acc1[q * 4 + 2] = fmaf(wv.z, xv1, acc1[q * 4 + 2]);
                acc0[q * 4 + 3] = fmaf(wv.w, xv0, acc0[q * 4 + 3]); acc1[q * 4 + 3] = fmaf(wv.w, xv1, acc1[q * 4 + 3]);
            }
        }
#pragma unroll
        for (int i = 0; i < 16; i++) {
            h2[0][g * 16 + i][k] = fmaxf(acc0[i], 0.0f);
            h2[1][g * 16 + i][k] = fmaxf(acc1[i], 0.0f);
        }
    }
    __syncthreads();

#pragma unroll
    for (int half = 0; half < 2; half++) {
        float acc0[16], acc1[16];
#pragma unroll
        for (int i = 0; i < 16; i++) { acc0[i] = b2f[g * 32 + half * 16 + i]; acc1[i] = acc0[i]; }
#pragma unroll 4
        for (int c = 0; c < 128; c++) {
            float xv0 = h2[0][c][k], xv1 = h2[1][c][k];
            const float4* wr = (const float4*)(W2t + c * 256 + g * 32 + half * 16);
#pragma unroll
            for (int q = 0; q < 4; q++) {
                float4 wv = wr[q];
                acc0[q * 4 + 0] = fmaf(wv.x, xv0, acc0[q * 4 + 0]); acc1[q * 4 + 0] = fmaf(wv.x, xv1, acc1[q * 4 + 0]);
                acc0[q * 4 + 1] = fmaf(wv.y, xv0, acc0[q * 4 + 1]); acc1[q * 4 + 1] = fmaf(wv.y, xv1, acc1[q * 4 + 1]);
                acc0[q * 4 + 2] = fmaf(wv.z, xv0, acc0[q * 4 + 2]); acc1[q * 4 + 2] = fmaf(wv.z, xv1, acc1[q * 4 + 2]);
                acc0[q * 4 + 3] = fmaf(wv.w, xv0, acc0[q * 4 + 3]); acc1[q * 4 + 3] = fmaf(wv.w, xv1, acc1[q * 4 + 3]);
            }
        }
#pragma unroll
        for (int i = 0; i < 16; i++) {
            float v0 = fmaxf(acc0[i], 0.0f);
            float v1 = fmaxf(acc1[i], 0.0f);
#pragma unroll
            for (int off = 16; off >= 1; off >>= 1) {
                v0 = fmaxf(v0, __shfl_xor(v0, off));
                v1 = fmaxf(v1, __shfl_xor(v1, off));
            }
            if (k == 0) {
                size_t o = (size_t)b * 256 + g * 32 + half * 16 + i;
                out_feat[o * NM + m0]     = v0;
                out_feat[o * NM + m0 + 1] = v1;
            }
        }
    }
}

extern "C" void kernel_launch(void* const* d_in, const int* in_sizes, int n_in,
                              void* d_out, int out_size, void* d_ws, size_t ws_size,
                              hipStream_t stream) {
    const float* xyz   = (const float*)d_in[0];
    const float* feats = (const float*)d_in[1];
    const float* W0 = (const float*)d_in[2];  const float* b0 = (const float*)d_in[3];
    const float* s0 = (const float*)d_in[4];  const float* t0 = (const float*)d_in[5];
    const float* W1 = (const float*)d_in[6];  const float* b1 = (const float*)d_in[7];
    const float* s1 = (const float*)d_in[8];  const float* t1 = (const float*)d_in[9];
    const float* W2 = (const float*)d_in[10]; const float* b2 = (const float*)d_in[11];
    const float* s2 = (const float*)d_in[12]; const float* t2 = (const float*)d_in[13];

    float* ws_f = (float*)d_ws;
    int*   idx_ws  = (int*)(ws_f + WS_IDX);
    float* nxyz_ws = ws_f + WS_NXYZ;
    int*   ball_ws = (int*)(ws_f + WS_BALL);

    float* out_f = (float*)d_out;
    float* out_xyz  = out_f + OUT_XYZ;
    float* out_feat = out_f + OUT_FEAT;
    float* out_idxf = out_f + OUT_IDX;

    prep_weights<<<179, 256, 0, stream>>>(W0, b0, s0, t0, W1, b1, s1, t1, W2, b2, s2, t2, ws_f);
    fps6_kernel<<<NB, 1024, 0, stream>>>(xyz, idx_ws);
    gather_newxyz<<<32, 256, 0, stream>>>(xyz, idx_ws, nxyz_ws, out_xyz, out_idxf);
    ball_query_kernel<<<NB * NM, 256, 0, stream>>>(xyz, nxyz_ws, ball_ws);
    fused_mlp_kernel<<<NB * NM / 2, 256, 0, stream>>>(xyz, feats, ws_f, ball_ws, nxyz_ws, out_feat);
}

// Round 14
// 2719.623 us; speedup vs baseline: 1.0952x; 1.0952x over previous
//
#include <hip/hip_runtime.h>
#include <stdint.h>

#define NB 8
#define NPT 16384
#define NM 1024
#define NK 32

// ws layout (float element offsets)
#define WS_W0T 0                    // 67*64 = 4288   W0t[c][o] = W0[o][c]*s0[o]
#define WS_B0  (WS_W0T + 4288)      // 64             b0*s0+t0
#define WS_W1T (WS_B0 + 64)         // 64*128 = 8192
#define WS_B1  (WS_W1T + 8192)      // 128
#define WS_W2T (WS_B1 + 128)        // 128*256 = 32768
#define WS_B2  (WS_W2T + 32768)     // 256
#define WS_IDX (WS_B2 + 256)        // 8192 ints (FPS indices)
#define WS_NXYZ (WS_IDX + 8192)     // 8*1024*3 = 24576 floats
#define WS_BALL (WS_NXYZ + 24576)   // 8*1024*32 = 262144 ints

// out layout (float element offsets)
#define OUT_XYZ 0
#define OUT_FEAT 24576
#define OUT_IDX (24576 + 2097152)

// ---------------- weight prep: transpose + fold BN scale ----------------
__global__ void prep_weights(const float* __restrict__ W0, const float* __restrict__ b0,
                             const float* __restrict__ s0, const float* __restrict__ t0,
                             const float* __restrict__ W1, const float* __restrict__ b1,
                             const float* __restrict__ s1, const float* __restrict__ t1,
                             const float* __restrict__ W2, const float* __restrict__ b2,
                             const float* __restrict__ s2, const float* __restrict__ t2,
                             float* __restrict__ ws) {
    int id = blockIdx.x * 256 + threadIdx.x;
    if (id < 4288) { int c = id >> 6, o = id & 63;  ws[WS_W0T + id] = W0[o * 67 + c] * s0[o]; return; }
    id -= 4288;
    if (id < 64)   { ws[WS_B0 + id] = fmaf(b0[id], s0[id], t0[id]); return; }
    id -= 64;
    if (id < 8192) { int c = id >> 7, o = id & 127; ws[WS_W1T + id] = W1[o * 64 + c] * s1[o]; return; }
    id -= 8192;
    if (id < 128)  { ws[WS_B1 + id] = fmaf(b1[id], s1[id], t1[id]); return; }
    id -= 128;
    if (id < 32768){ int c = id >> 8, o = id & 255; ws[WS_W2T + id] = W2[o * 128 + c] * s2[o]; return; }
    id -= 32768;
    if (id < 256)  { ws[WS_B2 + id] = fmaf(b2[id], s2[id], t2[id]); return; }
}

#define FOREACH16(M) M(0) M(1) M(2) M(3) M(4) M(5) M(6) M(7) \
                     M(8) M(9) M(10) M(11) M(12) M(13) M(14) M(15)

// DPP u32-max step (R13 fix: dpp_ctrl must be an IMMEDIATE -> template param).
// Invalid/unmasked lanes inherit `old`=v, so result is max over the reached set.
// ctrl: 0x111/112/114/118 = row_shr 1/2/4/8, 0x142 = row_bcast:15, 0x143 = row_bcast:31.
template <int CTRL>
__device__ __forceinline__ uint32_t dpp_max_step(uint32_t v) {
    uint32_t o = (uint32_t)__builtin_amdgcn_update_dpp((int)v, (int)v, CTRL, 0xf, 0xf, false);
    return v > o ? v : o;
}
// full wave64 max; valid in lane 63
__device__ __forceinline__ uint32_t wave_max_u32(uint32_t v) {
    v = dpp_max_step<0x111>(v);
    v = dpp_max_step<0x112>(v);
    v = dpp_max_step<0x114>(v);
    v = dpp_max_step<0x118>(v);
    v = dpp_max_step<0x142>(v);
    v = dpp_max_step<0x143>(v);
    return v;
}
// 16-lane row max; valid in lane 15 of each row
__device__ __forceinline__ uint32_t row_max_u32(uint32_t v) {
    v = dpp_max_step<0x111>(v);
    v = dpp_max_step<0x112>(v);
    v = dpp_max_step<0x114>(v);
    v = dpp_max_step<0x118>(v);
    return v;
}

// ---------------- farthest point sampling v7: LDS payload + DPP reduce ----------------
// fps6 (R12) fixed residency (VGPR=52, no spill) but kept a ~700-1000 cyc serial
// chain per iteration: 6-level u64 ds_bpermute butterfly + u64 LDS tail + dependent
// L2 centroid load. fps7 replaces the whole reduction with u32 DPP max chains
// (VALU-pipe, ~4-8 cyc/step). Exactness: all keys are non-negative float bits
// (dd >= 0), so u32 compare == f32 compare; tie-break via max(~idx) == min(idx);
// `old`-inheriting DPP steps never inject foreign values. readlane -> SGPR makes
// `farthest` uniform, so centroid loads become scalar loads (off the VALU path).
// Payload: (x,y) in LDS (128 KB), z+dd in 32 named-scalar VGPRs (fits: R12 VGPR=52).
// Distance math unchanged (_rn, no FMA) -> bit-matches reference.
__global__ __attribute__((amdgpu_flat_work_group_size(1024, 1024)))
void fps7_kernel(const float* __restrict__ xyz, int* __restrict__ out_idx) {
    __shared__ float2 pxy[NPT];          // 128 KB
    __shared__ uint2 s_red[2][16];       // {lo=~idx, hi=dist bits} per wave
    int b = blockIdx.x, t = threadIdx.x;
    const float* __restrict__ Xp = xyz + (size_t)b * NPT * 3;

#define DECL_PT(j) float pz##j, dd##j;
    FOREACH16(DECL_PT)
#undef DECL_PT

#define LOAD_PT(j) { int p = t + (j) * 1024; \
        float x = Xp[p * 3 + 0], y = Xp[p * 3 + 1]; \
        pz##j = Xp[p * 3 + 2]; \
        pxy[p] = make_float2(x, y); \
        dd##j = 1e10f; }
    FOREACH16(LOAD_PT)
#undef LOAD_PT
    __syncthreads();

    int farthest = 0;
    float cx = Xp[0], cy = Xp[1], cz = Xp[2];
    int lane = t & 63, w = t >> 6;
    for (int it = 0; it < NM; ++it) {
        if (t == 0) out_idx[b * NM + it] = farthest;
        float best = -1.0f; int bi = 0;
        // ascending j + strict '>' => first-max wins in-thread (idx = t + j*1024 ascends with j)
#define STEP_PT(j) { \
        float2 q = pxy[t + (j) * 1024]; \
        float dx = __fsub_rn(q.x, cx); \
        float dy = __fsub_rn(q.y, cy); \
        float dz = __fsub_rn(pz##j, cz); \
        float d  = __fadd_rn(__fadd_rn(__fmul_rn(dx, dx), __fmul_rn(dy, dy)), __fmul_rn(dz, dz)); \
        dd##j = fminf(dd##j, d); \
        if (dd##j > best) { best = dd##j; bi = t + (j) * 1024; } }
        FOREACH16(STEP_PT)
#undef STEP_PT
        // wave argmax: u32 DPP max of dist bits (best >= 0 after first point), then
        // exact tie-resolve: max of ~idx among lanes holding the max value.
        uint32_t bbits = __float_as_uint(best);
        uint32_t wmax = __builtin_amdgcn_readlane(wave_max_u32(bbits), 63);
        uint32_t cand = (bbits == wmax) ? ~(uint32_t)bi : 0u;
        uint32_t cwin = __builtin_amdgcn_readlane(wave_max_u32(cand), 63);
        if (lane == 0) s_red[it & 1][w] = make_uint2(cwin, wmax);
        __syncthreads();
        // 16-entry tail: row-only DPP (all rows read identical data)
        uint2 e = s_red[it & 1][lane & 15];
        uint32_t hmax = __builtin_amdgcn_readlane(row_max_u32(e.y), 15);
        uint32_t c2 = (e.y == hmax) ? e.x : 0u;
        uint32_t c2w = __builtin_amdgcn_readlane(row_max_u32(c2), 15);
        int widx = (int)(~c2w);
        farthest = widx;
        const float* cp = Xp + (size_t)widx * 3;   // widx is SGPR-uniform -> scalar loads
        cx = cp[0]; cy = cp[1]; cz = cp[2];
    }
}

// ---------------- gather new_xyz + emit indices as float ----------------
__global__ void gather_newxyz(const float* __restrict__ xyz, const int* __restrict__ idx_ws,
                              float* __restrict__ nxyz_ws, float* __restrict__ out_xyz,
                              float* __restrict__ out_idx_f) {
    int id = blockIdx.x * 256 + threadIdx.x;
    if (id >= NB * NM) return;
    int b = id / NM;
    int p = idx_ws[id];
    const float* Xp = xyz + ((size_t)b * NPT + p) * 3;
    float x = Xp[0], y = Xp[1], z = Xp[2];
    nxyz_ws[id * 3 + 0] = x; nxyz_ws[id * 3 + 1] = y; nxyz_ws[id * 3 + 2] = z;
    out_xyz[id * 3 + 0] = x; out_xyz[id * 3 + 1] = y; out_xyz[id * 3 + 2] = z;
    out_idx_f[id] = (float)p;
}

// ---------------- ball query: first 32 in-radius indices (ascending) ----------------
__global__ __launch_bounds__(256) void ball_query_kernel(const float* __restrict__ xyz,
                                                         const float* __restrict__ nxyz,
                                                         int* __restrict__ ball) {
    int blk = blockIdx.x;
    int b = blk >> 10;
    int t = threadIdx.x;
    const float* Xp = xyz + (size_t)b * NPT * 3;
    float cx = nxyz[blk * 3 + 0], cy = nxyz[blk * 3 + 1], cz = nxyz[blk * 3 + 2];
    const float r2 = (float)(0.4 * 0.4);
    uint64_t mask = 0;
    int base = t * 64;
    const float4* q = (const float4*)(Xp + (size_t)base * 3);
#pragma unroll 4
    for (int c = 0; c < 16; c++) {
        float4 A = q[c * 3 + 0], B = q[c * 3 + 1], C = q[c * 3 + 2];
        float xs[4] = {A.x, A.w, B.z, C.y};
        float ys[4] = {A.y, B.x, B.w, C.z};
        float zs[4] = {A.z, B.y, C.x, C.w};
#pragma unroll
        for (int u = 0; u < 4; u++) {
            float dx = __fsub_rn(xs[u], cx);
            float dy = __fsub_rn(ys[u], cy);
            float dz = __fsub_rn(zs[u], cz);
            float d2 = __fadd_rn(__fadd_rn(__fmul_rn(dx, dx), __fmul_rn(dy, dy)), __fmul_rn(dz, dz));
            if (d2 <= r2) mask |= (1ull << (c * 4 + u));
        }
    }
    int cnt = __popcll(mask);
    int scan = cnt;
    for (int off = 1; off < 64; off <<= 1) {
        int nv = __shfl_up(scan, off);
        if ((t & 63) >= off) scan += nv;
    }
    __shared__ int s_wsum[4];
    __shared__ int s_hit[32];
    int w = t >> 6;
    if ((t & 63) == 63) s_wsum[w] = scan;
    __syncthreads();
    int woff = 0;
    for (int i = 0; i < 4; i++) if (i < w) woff += s_wsum[i];
    int excl = woff + scan - cnt;
    uint64_t mm = mask; int pos = excl;
    while (mm && pos < 32) {
        int j = __ffsll((long long)mm) - 1;
        s_hit[pos] = base + j;
        pos++;
        mm &= mm - 1;
    }
    __syncthreads();
    int total = s_wsum[0] + s_wsum[1] + s_wsum[2] + s_wsum[3];
    if (t < 32) {
        int first = s_hit[0];
        ball[blk * NK + t] = (t < total) ? s_hit[t] : first;
    }
}

// ---------------- fused group + 3xMLP + max over K ----------------
__global__ __attribute__((amdgpu_flat_work_group_size(256, 256), amdgpu_waves_per_eu(2, 2)))
void fused_mlp_kernel(const float* __restrict__ xyz,
                      const float* __restrict__ feats,
                      const float* __restrict__ ws_f,
                      const int* __restrict__ ball,
                      const float* __restrict__ nxyz,
                      float* __restrict__ out_feat) {
    int blk = blockIdx.x;
    int b = blk >> 9;
    int m0 = (blk & 511) * 2;
    int t = threadIdx.x;
    int k = t & 31, g = t >> 5;
    __shared__ float Xs[2][67][32];
    __shared__ float h1[2][64][32];
    __shared__ float h2[2][128][32];
    __shared__ int sidx[2][32];
    const float* W0t = ws_f + WS_W0T; const float* b0f = ws_f + WS_B0;
    const float* W1t = ws_f + WS_W1T; const float* b1f = ws_f + WS_B1;
    const float* W2t = ws_f + WS_W2T; const float* b2f = ws_f + WS_B2;

    if (t < 64) {
        int ctr = t >> 5;
        sidx[ctr][t & 31] = ball[((size_t)b * NM + m0 + ctr) * NK + (t & 31)];
    }
    __syncthreads();

    const float* Xp = xyz + (size_t)b * NPT * 3;
    if (g < 6) {
        int ctr = g / 3, dim = g % 3;
        float cc = nxyz[((size_t)b * NM + m0 + ctr) * 3 + dim];
        Xs[ctr][dim][k] = Xp[sidx[ctr][k] * 3 + dim] - cc;
    }
    const float* Fp = feats + (size_t)b * 64 * NPT;
#pragma unroll
    for (int i = 0; i < 8; i++) {
        int c = g + 8 * i;
        Xs[0][3 + c][k] = Fp[(size_t)c * NPT + sidx[0][k]];
        Xs[1][3 + c][k] = Fp[(size_t)c * NPT + sidx[1][k]];
    }
    __syncthreads();

    {
        float acc0[8], acc1[8];
#pragma unroll
        for (int i = 0; i < 8; i++) { acc0[i] = b0f[g * 8 + i]; acc1[i] = acc0[i]; }
#pragma unroll 4
        for (int c = 0; c < 67; c++) {
            float xv0 = Xs[0][c][k], xv1 = Xs[1][c][k];
            const float* wr = W0t + c * 64 + g * 8;
            float4 wa = *(const float4*)(wr), wb = *(const float4*)(wr + 4);
            acc0[0] = fmaf(wa.x, xv0, acc0[0]); acc1[0] = fmaf(wa.x, xv1, acc1[0]);
            acc0[1] = fmaf(wa.y, xv0, acc0[1]); acc1[1] = fmaf(wa.y, xv1, acc1[1]);
            acc0[2] = fmaf(wa.z, xv0, acc0[2]); acc1[2] = fmaf(wa.z, xv1, acc1[2]);
            acc0[3] = fmaf(wa.w, xv0, acc0[3]); acc1[3] = fmaf(wa.w, xv1, acc1[3]);
            acc0[4] = fmaf(wb.x, xv0, acc0[4]); acc1[4] = fmaf(wb.x, xv1, acc1[4]);
            acc0[5] = fmaf(wb.y, xv0, acc0[5]); acc1[5] = fmaf(wb.y, xv1, acc1[5]);
            acc0[6] = fmaf(wb.z, xv0, acc0[6]); acc1[6] = fmaf(wb.z, xv1, acc1[6]);
            acc0[7] = fmaf(wb.w, xv0, acc0[7]); acc1[7] = fmaf(wb.w, xv1, acc1[7]);
        }
#pragma unroll
        for (int i = 0; i < 8; i++) {
            h1[0][g * 8 + i][k] = fmaxf(acc0[i], 0.0f);
            h1[1][g * 8 + i][k] = fmaxf(acc1[i], 0.0f);
        }
    }
    __syncthreads();

    {
        float acc0[16], acc1[16];
#pragma unroll
        for (int i = 0; i < 16; i++) { acc0[i] = b1f[g * 16 + i]; acc1[i] = acc0[i]; }
#pragma unroll 4
        for (int c = 0; c < 64; c++) {
            float xv0 = h1[0][c][k], xv1 = h1[1][c][k];
            const float4* wr = (const float4*)(W1t + c * 128 + g * 16);
#pragma unroll
            for (int q = 0; q < 4; q++) {
                float4 wv = wr[q];
                acc0[q * 4 + 0] = fmaf(wv.x, xv0, acc0[q * 4 + 0]); acc1[q * 4 + 0] = fmaf(wv.x, xv1, acc1[q * 4 + 0]);
                acc0[q * 4 + 1] = fmaf(wv.y, xv0, acc0[q * 4 + 1]); acc1[q * 4 + 1] = fmaf(wv.y, xv1, acc1[q * 4 + 1]);
                acc0[q * 4 + 2] = fmaf(wv.z, xv0, acc0[q * 4 + 2]); acc1[q * 4 + 2] = fmaf(wv.z, xv1, acc1[q * 4 + 2]);
                acc0[q * 4 + 3] = fmaf(wv.w, xv0, acc0[q * 4 + 3]); acc1[q * 4 + 3] = fmaf(wv.w, xv1, acc1[q * 4 + 3]);
            }
        }
#pragma unroll
        for (int i = 0; i < 16; i++) {
            h2[0][g * 16 + i][k] = fmaxf(acc0[i], 0.0f);
            h2[1][g * 16 + i][k] = fmaxf(acc1[i], 0.0f);
        }
    }
    __syncthreads();

#pragma unroll
    for (int half = 0; half < 2; half++) {
        float acc0[16], acc1[16];
#pragma unroll
        for (int i = 0; i < 16; i++) { acc0[i] = b2f[g * 32 + half * 16 + i]; acc1[i] = acc0[i]; }
#pragma unroll 4
        for (int c = 0; c < 128; c++) {
            float xv0 = h2[0][c][k], xv1 = h2[1][c][k];
            const float4* wr = (const float4*)(W2t + c * 256 + g * 32 + half * 16);
#pragma unroll
            for (int q = 0; q < 4; q++) {
                float4 wv = wr[q];
                acc0[q * 4 + 0] = fmaf(wv.x, xv0, acc0[q * 4 + 0]); acc1[q * 4 + 0] = fmaf(wv.x, xv1, acc1[q * 4 + 0]);
                acc0[q * 4 + 1] = fmaf(wv.y, xv0, acc0[q * 4 + 1]); acc1[q * 4 + 1] = fmaf(wv.y, xv1, acc1[q * 4 + 1]);
                acc0[q * 4 + 2] = fmaf(wv.z, xv0, acc0[q * 4 + 2]); acc1[q * 4 + 2] = fmaf(wv.z, xv1, acc1[q * 4 + 2]);
                acc0[q * 4 + 3] = fmaf(wv.w, xv0, acc0[q * 4 + 3]); acc1[q * 4 + 3] = fmaf(wv.w, xv1, acc1[q * 4 + 3]);
            }
        }
#pragma unroll
        for (int i = 0; i < 16; i++) {
            float v0 = fmaxf(acc0[i], 0.0f);
            float v1 = fmaxf(acc1[i], 0.0f);
#pragma unroll
            for (int off = 16; off >= 1; off >>= 1) {
                v0 = fmaxf(v0, __shfl_xor(v0, off));
                v1 = fmaxf(v1, __shfl_xor(v1, off));
            }
            if (k == 0) {
                size_t o = (size_t)b * 256 + g * 32 + half * 16 + i;
                out_feat[o * NM + m0]     = v0;
                out_feat[o * NM + m0 + 1] = v1;
            }
        }
    }
}

extern "C" void kernel_launch(void* const* d_in, const int* in_sizes, int n_in,
                              void* d_out, int out_size, void* d_ws, size_t ws_size,
                              hipStream_t stream) {
    const float* xyz   = (const float*)d_in[0];
    const float* feats = (const float*)d_in[1];
    const float* W0 = (const float*)d_in[2];  const float* b0 = (const float*)d_in[3];
    const float* s0 = (const float*)d_in[4];  const float* t0 = (const float*)d_in[5];
    const float* W1 = (const float*)d_in[6];  const float* b1 = (const float*)d_in[7];
    const float* s1 = (const float*)d_in[8];  const float* t1 = (const float*)d_in[9];
    const float* W2 = (const float*)d_in[10]; const float* b2 = (const float*)d_in[11];
    const float* s2 = (const float*)d_in[12]; const float* t2 = (const float*)d_in[13];

    float* ws_f = (float*)d_ws;
    int*   idx_ws  = (int*)(ws_f + WS_IDX);
    float* nxyz_ws = ws_f + WS_NXYZ;
    int*   ball_ws = (int*)(ws_f + WS_BALL);

    float* out_f = (float*)d_out;
    float* out_xyz  = out_f + OUT_XYZ;
    float* out_feat = out_f + OUT_FEAT;
    float* out_idxf = out_f + OUT_IDX;

    prep_weights<<<179, 256, 0, stream>>>(W0, b0, s0, t0, W1, b1, s1, t1, W2, b2, s2, t2, ws_f);
    fps7_kernel<<<NB, 1024, 0, stream>>>(xyz, idx_ws);
    gather_newxyz<<<32, 256, 0, stream>>>(xyz, idx_ws, nxyz_ws, out_xyz, out_idxf);
    ball_query_kernel<<<NB * NM, 256, 0, stream>>>(xyz, nxyz_ws, ball_ws);
    fused_mlp_kernel<<<NB * NM / 2, 256, 0, stream>>>(xyz, feats, ws_f, ball_ws, nxyz_ws, out_feat);
}